// Round 4
// baseline (849.969 us; speedup 1.0000x reference)
//
#include <hip/hip_runtime.h>

// ---------------------------------------------------------------------------
// Zernike 5x5 conv, 8 in-ch -> 16 out-ch, B=8, H=W=1024, pad=2.
// R2 restructure: (1) streaming pre-pass converts NCHW f32 -> NHWC bf16
// (channels-last, 16B/pixel) into workspace; (2) conv stages pixels into LDS
// via global_load_lds (pure DMA, no pack VALU), implicit GEMM via
// mfma_f32_16x16x32_bf16, weights split hi+lo bf16. Numerics identical to R1.
// Workspace layout: [0,14336) whi/wlo, [16384,16448) zero block,
// [32768, 32768+128MB) NHWC bf16 image. Evidence for 2 GiB ws: harness
// poison fills of exactly 2^31 bytes.
// ---------------------------------------------------------------------------

typedef __attribute__((ext_vector_type(8))) short bf16x8;  // 8 bf16 = 4 VGPRs
typedef __attribute__((ext_vector_type(4))) float f32x4;

#define OUT_CH 16
#define IN_CH  8
#define NTAPS  28          // 25 real taps padded to 28 (7 k-blocks of 4 taps)
#define IMG    1024
#define TH     16          // output tile rows per block
#define TW     64          // output tile cols per block
#define LR     (TH + 4)    // 20 halo rows
#define LC     (TW + 4)    // 68 halo cols
#define NPIX   (LR * LC)   // 1360 staged pixels
#define NPIXP  1536        // padded to 6 * 256 for uniform staging loop

#define GLOBAL_AS __attribute__((address_space(1)))
#define LDS_AS    __attribute__((address_space(3)))

static __device__ __forceinline__ unsigned short f32_to_bf16_rne(float f) {
    unsigned int u = __float_as_uint(f);
    u = u + 0x7fffu + ((u >> 16) & 1u);   // round-to-nearest-even
    return (unsigned short)(u >> 16);
}
static __device__ __forceinline__ float bf16_bits_to_f32(unsigned short h) {
    return __uint_as_float(((unsigned int)h) << 16);
}
static __device__ __forceinline__ unsigned int pk2(float lo, float hi) {
    return (unsigned int)f32_to_bf16_rne(lo) |
           ((unsigned int)f32_to_bf16_rne(hi) << 16);
}

// ---------------------------------------------------------------------------
// Kernel 1: packed weights w[co][tap][ci] as bf16 hi + lo; also zero-fills
// the 64B zero-source block used by conv staging for out-of-bounds lanes.
// ---------------------------------------------------------------------------
__global__ void zernike_weights_kernel(const float* __restrict__ coeff,
                                       const int* __restrict__ expn,
                                       const int* __restrict__ nvals,
                                       int K, int S,
                                       unsigned short* __restrict__ whi,
                                       unsigned short* __restrict__ wlo,
                                       unsigned int* __restrict__ zeropad) {
    int idx = blockIdx.x * blockDim.x + threadIdx.x;
    if (blockIdx.x == 0 && threadIdx.x < 16) zeropad[threadIdx.x] = 0u;
    if (idx >= K * NTAPS) return;
    int p   = idx / NTAPS;
    int tap = idx - p * NTAPS;
    const float CENTER = 2.0f;                 // FILT/2 - 0.5
    const float CUTOFF = sqrtf(4.25f);         // sqrt(CENTER^2 + 0.25)
    const float LNE    = 0.99999932734f;       // ln(2.71828)
    int co = p >> 3, ci = p & 7;
    float nv = (float)nvals[p];

    float w = 0.0f;
    if (tap < 25) {
        int i = tap / 5, j = tap % 5;
        float a = fabsf((float)i - CENTER);
        float b = fabsf((float)j - CENTER);
        float dist = sqrtf(a * a + b * b);
        float radial = (dist <= CUTOFF) ? dist : 0.0f;
        float rsafe = (radial > 0.0f) ? radial : 1.0f;
        float poly = 0.0f;
        for (int s = 0; s < S; ++s) {
            float C = coeff[p * S + s];
            int   e = expn[p * S + s];
            float pw = 1.0f;
            for (int t = 0; t < e; ++t) pw *= rsafe;
            poly += C * pw;
        }
        if (!(radial > 0.0f)) poly = 0.0f;
        float phi  = atanf(b / (a + 0.001f));
        float cosr = cosf(nv * phi * LNE);
        w = (poly > 0.0f) ? poly * cosr : poly;
    }
    unsigned short hi = f32_to_bf16_rne(w);
    unsigned short lo = f32_to_bf16_rne(w - bf16_bits_to_f32(hi));
    int oidx = (co * NTAPS + tap) * 8 + ci;
    whi[oidx] = hi;
    wlo[oidx] = lo;
}

// ---------------------------------------------------------------------------
// Kernel 2: NCHW f32 -> NHWC bf16 (RNE), 16B per pixel (8 channels).
// One block per (b,y) row; thread t handles pixels 4t..4t+3.
// Loads: 8 x float4 coalesced per channel; stores: 64B contiguous per thread.
// ---------------------------------------------------------------------------
__global__ __launch_bounds__(256) void cvt_nhwc_kernel(
        const float* __restrict__ x, uint4* __restrict__ xp) {
    const int t   = threadIdx.x;
    const int row = blockIdx.x;                    // b*1024 + y
    const float* px = x + (((long)(row >> 10)) << 23)    // batch: 8M floats
                        + ((long)(row & 1023) << 10);    // row: 1024 floats
    const int px0 = t << 2;
    f32x4 v[8];
#pragma unroll
    for (int ci = 0; ci < 8; ++ci)
        v[ci] = *(const f32x4*)(px + ((long)ci << 20) + px0);
    uint4* dst = xp + (((long)row << 10) + px0);
#pragma unroll
    for (int j = 0; j < 4; ++j) {
        uint4 u;
        u.x = pk2(v[0][j], v[1][j]);
        u.y = pk2(v[2][j], v[3][j]);
        u.z = pk2(v[4][j], v[5][j]);
        u.w = pk2(v[6][j], v[7][j]);
        dst[j] = u;
    }
}

// ---------------------------------------------------------------------------
// Kernel 3: tiled implicit-GEMM conv reading NHWC bf16.
// Block: 256 threads (4 waves). Tile: 16 rows x 64 cols of output.
// Staging: global_load_lds width 16, one pixel (8ch bf16) per lane, linear
// LDS dest (wave-uniform base + lane*16); OOB lanes source the zero block.
// LDS: 1536 * 16B = 24.6 KB.
// ---------------------------------------------------------------------------
__global__ __launch_bounds__(256) void conv_mfma_kernel(
        const uint4* __restrict__ xp,
        const uint4* __restrict__ zsrc,
        const unsigned short* __restrict__ whi,
        const unsigned short* __restrict__ wlo,
        float* __restrict__ out) {
    __shared__ uint4 tile[NPIXP];

    const int tx   = blockIdx.x * TW;
    const int ty   = blockIdx.y * TH;
    const int b    = blockIdx.z;
    const int tid  = threadIdx.x;
    const int lane = tid & 63;
    const int wv   = tid >> 6;
    const int quad = lane >> 4;
    const int n15  = lane & 15;

    // ---- A fragments (weights): A[m=lane&15][k=quad*8+j], k = tap*8+ci ----
    bf16x8 a_hi[7], a_lo[7];
#pragma unroll
    for (int q = 0; q < 7; ++q) {
        int tap = q * 4 + quad;
        int off = (n15 * NTAPS + tap) * 8;
        a_hi[q] = *(const bf16x8*)(whi + off);
        a_lo[q] = *(const bf16x8*)(wlo + off);
    }

    // ---- Stage 1360 halo pixels (padded to 1536) via direct-to-LDS DMA ----
#pragma unroll
    for (int k = 0; k < 6; ++k) {
        int p  = k * 256 + tid;
        int r  = p / LC;
        int c  = p - r * LC;
        int gy = ty + r - 2;
        int gx = tx + c - 2;
        bool inb = (r < LR) & ((unsigned)gy < IMG) & ((unsigned)gx < IMG);
        const uint4* src = inb ? (xp + ((b << 20) + (gy << 10) + gx)) : zsrc;
        __builtin_amdgcn_global_load_lds(
            (GLOBAL_AS const void*)src,
            (LDS_AS void*)&tile[p], 16, 0, 0);
    }
    __syncthreads();   // drains vmcnt before barrier

    // ---- per-q LDS pixel offsets (tap -> kh,kw); col origin is tx-2 ----
    int offq[7];
#pragma unroll
    for (int q = 0; q < 7; ++q) {
        int tap = q * 4 + quad;
        int kh = (tap < 25) ? (tap / 5) : 0;
        int kw = (tap < 25) ? (tap % 5) : 0;
        offq[q] = kh * LC + kw;
    }

    const int row0 = wv * 4;
#pragma unroll
    for (int gr = 0; gr < 4; ++gr) {
        int row = row0 + gr;
#pragma unroll
        for (int gc = 0; gc < 4; ++gc) {
            int c0   = gc * 16;
            int base = row * LC + c0 + n15;
            f32x4 acc_h = {0.f, 0.f, 0.f, 0.f};
            f32x4 acc_l = {0.f, 0.f, 0.f, 0.f};
#pragma unroll
            for (int q = 0; q < 7; ++q) {
                bf16x8 bfrag = *(const bf16x8*)&tile[base + offq[q]];
                acc_h = __builtin_amdgcn_mfma_f32_16x16x32_bf16(a_hi[q], bfrag, acc_h, 0, 0, 0);
                acc_l = __builtin_amdgcn_mfma_f32_16x16x32_bf16(a_lo[q], bfrag, acc_l, 0, 0, 0);
            }
            // C/D: col = lane&15 (pixel), row = quad*4 + reg (out channel)
            int gy  = ty + row;
            int gxp = tx + c0 + n15;
#pragma unroll
            for (int r = 0; r < 4; ++r) {
                int co = quad * 4 + r;
                out[(((b * OUT_CH + co) << 10) + gy << 10) + gxp] = acc_h[r] + acc_l[r];
            }
        }
    }
}

extern "C" void kernel_launch(void* const* d_in, const int* in_sizes, int n_in,
                              void* d_out, int out_size, void* d_ws, size_t ws_size,
                              hipStream_t stream) {
    const float* x     = (const float*)d_in[0];
    const float* coeff = (const float*)d_in[1];
    const int*   expn  = (const int*)d_in[2];
    const int*   nvals = (const int*)d_in[3];
    int K = in_sizes[3];              // 128
    int S = in_sizes[1] / K;          // 7

    unsigned short* whi  = (unsigned short*)d_ws;
    unsigned short* wlo  = whi + OUT_CH * NTAPS * 8;             // 3584 shorts
    unsigned int*   zpad = (unsigned int*)((char*)d_ws + 16384); // 64B zeros
    uint4*          xp   = (uint4*)((char*)d_ws + 32768);        // 128 MB NHWC bf16

    int wthreads = K * NTAPS;         // 3584
    zernike_weights_kernel<<<(wthreads + 255) / 256, 256, 0, stream>>>(
        coeff, expn, nvals, K, S, whi, wlo, zpad);

    cvt_nhwc_kernel<<<8 * IMG, 256, 0, stream>>>(x, xp);

    dim3 grid(IMG / TW, IMG / TH, 8);
    conv_mfma_kernel<<<grid, 256, 0, stream>>>(xp, (const uint4*)zpad, whi, wlo, (float*)d_out);
}

// Round 5
// 794.102 us; speedup vs baseline: 1.0704x; 1.0704x over previous
//
#include <hip/hip_runtime.h>

// ---------------------------------------------------------------------------
// Zernike 5x5 conv, 8 in-ch -> 16 out-ch, B=8, H=W=1024, pad=2.
// R5: revert R4's separate NHWC pre-pass (net-negative: added 384 MB traffic,
// +44 us). Fused conv with float4-aligned pack staging (R2 structure, 806 us)
// + TH=32 tile (halo read factor 1.44 -> 1.27). Conv is effective-BW-bound:
// R4's pure-DMA staging showed staging style doesn't move total time.
// ---------------------------------------------------------------------------

typedef __attribute__((ext_vector_type(8))) short bf16x8;  // 8 bf16 = 4 VGPRs
typedef __attribute__((ext_vector_type(4))) float f32x4;

#define OUT_CH 16
#define IN_CH  8
#define NTAPS  28          // 25 real taps padded to 28 (7 k-blocks of 4 taps)
#define IMG    1024
#define TH     32          // output tile rows per block
#define TW     64          // output tile cols per block
#define LR     (TH + 4)    // 36 halo rows
#define LC     72          // 72 halo cols: [tx-4, tx+68), all float4-aligned
#define CGRP   (LC / 4)    // 18 col-groups per row

static __device__ __forceinline__ unsigned short f32_to_bf16_rne(float f) {
    unsigned int u = __float_as_uint(f);
    u = u + 0x7fffu + ((u >> 16) & 1u);   // round-to-nearest-even
    return (unsigned short)(u >> 16);
}
static __device__ __forceinline__ float bf16_bits_to_f32(unsigned short h) {
    return __uint_as_float(((unsigned int)h) << 16);
}
static __device__ __forceinline__ unsigned int pk2(float lo, float hi) {
    return (unsigned int)f32_to_bf16_rne(lo) |
           ((unsigned int)f32_to_bf16_rne(hi) << 16);
}

// ---------------------------------------------------------------------------
// Kernel 1: packed weights w[co][tap][ci] as bf16 hi + lo.
// One thread per (pair, tap): K*NTAPS = 3584 threads across 14 blocks.
// ---------------------------------------------------------------------------
__global__ void zernike_weights_kernel(const float* __restrict__ coeff,
                                       const int* __restrict__ expn,
                                       const int* __restrict__ nvals,
                                       int K, int S,
                                       unsigned short* __restrict__ whi,
                                       unsigned short* __restrict__ wlo) {
    int idx = blockIdx.x * blockDim.x + threadIdx.x;
    if (idx >= K * NTAPS) return;
    int p   = idx / NTAPS;
    int tap = idx - p * NTAPS;
    const float CENTER = 2.0f;                 // FILT/2 - 0.5
    const float CUTOFF = sqrtf(4.25f);         // sqrt(CENTER^2 + 0.25)
    const float LNE    = 0.99999932734f;       // ln(2.71828)
    int co = p >> 3, ci = p & 7;
    float nv = (float)nvals[p];

    float w = 0.0f;
    if (tap < 25) {
        int i = tap / 5, j = tap % 5;
        float a = fabsf((float)i - CENTER);
        float b = fabsf((float)j - CENTER);
        float dist = sqrtf(a * a + b * b);
        float radial = (dist <= CUTOFF) ? dist : 0.0f;
        float rsafe = (radial > 0.0f) ? radial : 1.0f;
        float poly = 0.0f;
        for (int s = 0; s < S; ++s) {
            float C = coeff[p * S + s];
            int   e = expn[p * S + s];
            float pw = 1.0f;
            for (int t = 0; t < e; ++t) pw *= rsafe;
            poly += C * pw;
        }
        if (!(radial > 0.0f)) poly = 0.0f;
        float phi  = atanf(b / (a + 0.001f));
        float cosr = cosf(nv * phi * LNE);
        w = (poly > 0.0f) ? poly * cosr : poly;
    }
    unsigned short hi = f32_to_bf16_rne(w);
    unsigned short lo = f32_to_bf16_rne(w - bf16_bits_to_f32(hi));
    int oidx = (co * NTAPS + tap) * 8 + ci;
    whi[oidx] = hi;
    wlo[oidx] = lo;
}

// ---------------------------------------------------------------------------
// Kernel 2: tiled implicit-GEMM conv.
// Block: 256 threads (4 waves). Tile: 32 rows x 64 cols of output.
// LDS: 36x72 pixels, channels-last bf16x8 (uint4), 41.47 KB (3 blocks/CU).
// Staging: aligned float4 per (4-pixel, channel) group; groups are fully
// in-bounds or fully out (gx0 multiple of 4, bounds multiples of 4).
// ---------------------------------------------------------------------------
__global__ __launch_bounds__(256) void conv_mfma_kernel(
        const float* __restrict__ x,
        const unsigned short* __restrict__ whi,
        const unsigned short* __restrict__ wlo,
        float* __restrict__ out) {
    __shared__ uint4 tile[LR * LC];

    const int tx   = blockIdx.x * TW;
    const int ty   = blockIdx.y * TH;
    const int b    = blockIdx.z;
    const int tid  = threadIdx.x;
    const int lane = tid & 63;
    const int wv   = tid >> 6;
    const int quad = lane >> 4;
    const int n15  = lane & 15;

    // ---- A fragments (weights): A[m=lane&15][k=quad*8+j], k = tap*8+ci ----
    bf16x8 a_hi[7], a_lo[7];
#pragma unroll
    for (int q = 0; q < 7; ++q) {
        int tap = q * 4 + quad;
        int off = (n15 * NTAPS + tap) * 8;
        a_hi[q] = *(const bf16x8*)(whi + off);
        a_lo[q] = *(const bf16x8*)(wlo + off);
    }

    // ---- Stage input tile: channels-last bf16, float4 loads ----
    const float* xb = x + (((long)b * IN_CH) << 20);
    for (int g = tid; g < LR * CGRP; g += 256) {
        int r   = g / CGRP;
        int cg  = g - r * CGRP;
        int gy  = ty + r - 2;
        int gx0 = tx + (cg << 2) - 4;
        uint4 u[4];
        if (((unsigned)gy < IMG) & ((unsigned)gx0 < IMG)) {
            const float* px = xb + (gy << 10) + gx0;
            f32x4 v[8];
#pragma unroll
            for (int ci = 0; ci < 8; ++ci)
                v[ci] = *(const f32x4*)(px + (ci << 20));
#pragma unroll
            for (int j = 0; j < 4; ++j) {
                u[j].x = pk2(v[0][j], v[1][j]);
                u[j].y = pk2(v[2][j], v[3][j]);
                u[j].z = pk2(v[4][j], v[5][j]);
                u[j].w = pk2(v[6][j], v[7][j]);
            }
        } else {
#pragma unroll
            for (int j = 0; j < 4; ++j) {
                u[j].x = 0u; u[j].y = 0u; u[j].z = 0u; u[j].w = 0u;
            }
        }
        int t0 = r * LC + (cg << 2);
#pragma unroll
        for (int j = 0; j < 4; ++j) tile[t0 + j] = u[j];
    }
    __syncthreads();

    // ---- per-q LDS pixel offsets (tap -> kh,kw); col origin is tx-4 ----
    int offq[7];
#pragma unroll
    for (int q = 0; q < 7; ++q) {
        int tap = q * 4 + quad;
        int kh = (tap < 25) ? (tap / 5) : 0;
        int kw = (tap < 25) ? (tap % 5) : 0;
        offq[q] = kh * LC + kw + 2;   // col origin tx-4, pad 2 => +2
    }

    const int row0 = wv * (TH / 4);   // 8 rows per wave
#pragma unroll
    for (int gr = 0; gr < TH / 4; ++gr) {
        int row = row0 + gr;
#pragma unroll
        for (int gc = 0; gc < 4; ++gc) {
            int c0   = gc * 16;
            int base = row * LC + c0 + n15;
            f32x4 acc_h = {0.f, 0.f, 0.f, 0.f};
            f32x4 acc_l = {0.f, 0.f, 0.f, 0.f};
#pragma unroll
            for (int q = 0; q < 7; ++q) {
                bf16x8 bfrag = *(const bf16x8*)&tile[base + offq[q]];
                acc_h = __builtin_amdgcn_mfma_f32_16x16x32_bf16(a_hi[q], bfrag, acc_h, 0, 0, 0);
                acc_l = __builtin_amdgcn_mfma_f32_16x16x32_bf16(a_lo[q], bfrag, acc_l, 0, 0, 0);
            }
            // C/D: col = lane&15 (pixel), row = quad*4 + reg (out channel)
            int gy  = ty + row;
            int gxp = tx + c0 + n15;
#pragma unroll
            for (int r = 0; r < 4; ++r) {
                int co = quad * 4 + r;
                out[(((b * OUT_CH + co) << 10) + gy << 10) + gxp] = acc_h[r] + acc_l[r];
            }
        }
    }
}

extern "C" void kernel_launch(void* const* d_in, const int* in_sizes, int n_in,
                              void* d_out, int out_size, void* d_ws, size_t ws_size,
                              hipStream_t stream) {
    const float* x     = (const float*)d_in[0];
    const float* coeff = (const float*)d_in[1];
    const int*   expn  = (const int*)d_in[2];
    const int*   nvals = (const int*)d_in[3];
    int K = in_sizes[3];              // 128
    int S = in_sizes[1] / K;          // 7

    unsigned short* whi = (unsigned short*)d_ws;
    unsigned short* wlo = whi + OUT_CH * NTAPS * 8;   // 3584 shorts, 16B aligned

    int wthreads = K * NTAPS;         // 3584
    zernike_weights_kernel<<<(wthreads + 255) / 256, 256, 0, stream>>>(
        coeff, expn, nvals, K, S, whi, wlo);

    dim3 grid(IMG / TW, IMG / TH, 8);
    conv_mfma_kernel<<<grid, 256, 0, stream>>>(x, whi, wlo, (float*)d_out);
}